// Round 11
// baseline (237.092 us; speedup 1.0000x reference)
//
#include <hip/hip_runtime.h>

#define N_NODES 100000
#define N_EDGES 1600000
#define D_FEAT 64

#define N_PART 8
#define SLICE  (N_EDGES / N_PART)          // 200000, exact; divisible by 4

#define RB_LOG 7
#define ROWS_PER_BUCKET 128
#define N_BUCKET ((N_NODES + ROWS_PER_BUCKET - 1) / ROWS_PER_BUCKET)  // 782
#define N_CELL (N_BUCKET * N_PART)         // 6256

#define COL_BITS 17
#define COL_MASK ((1 << COL_BITS) - 1)

#define CAP 512        // slots per (bucket,part) cell; mean 256, 16-sigma margin
#define MAXREC 2048    // 21 KB LDS -> ~7 blocks/CU
#define PAD 16         // one contended counter per 64B line
#define OVF_MAX 4096

// ------- scatter: append edges into fixed-capacity (bucket,part) cells -----
// 4 edges per thread per iter via int4/float4 loads -> 4 independent
// atomic+store chains in flight.
__global__ __launch_bounds__(256) void scatter_kernel(
    const float* __restrict__ vals, const int* __restrict__ rows,
    const int* __restrict__ cols, int* __restrict__ cursor,
    int2* __restrict__ rec, int4* __restrict__ ovf, int* __restrict__ ovf_cnt)
{
    int part = blockIdx.x & (N_PART - 1);
    int blk  = blockIdx.x >> 3;
    int nblk = gridDim.x >> 3;
    int base = part * SLICE;

    const int4*   rows4 = reinterpret_cast<const int4*>(rows + base);
    const int4*   cols4 = reinterpret_cast<const int4*>(cols + base);
    const float4* vals4 = reinterpret_cast<const float4*>(vals + base);
    const int ngrp = SLICE / 4;   // 50000

    for (int g = blk * 256 + threadIdx.x; g < ngrp; g += nblk * 256) {
        int4   r4 = rows4[g];
        int4   c4 = cols4[g];
        float4 v4 = vals4[g];

        int r[4] = {r4.x, r4.y, r4.z, r4.w};
        int c[4] = {c4.x, c4.y, c4.z, c4.w};
        float v[4] = {v4.x, v4.y, v4.z, v4.w};

        int pos[4], cell[4];
        #pragma unroll
        for (int j = 0; j < 4; ++j) {
            cell[j] = (r[j] >> RB_LOG) * N_PART + part;
            pos[j]  = atomicAdd(&cursor[cell[j] * PAD], 1);
        }
        #pragma unroll
        for (int j = 0; j < 4; ++j) {
            if (pos[j] < CAP) {
                int packed = ((r[j] & (ROWS_PER_BUCKET - 1)) << COL_BITS) | c[j];
                rec[cell[j] * CAP + pos[j]] = make_int2(packed, __float_as_int(v[j]));
            } else {
                int opos = atomicAdd(ovf_cnt, 1);
                if (opos < OVF_MAX)
                    ovf[opos] = make_int4(r[j], c[j], __float_as_int(v[j]), 0);
            }
        }
    }
}

// ---- gather: per-bucket LDS index-sort + register accumulate --------------
__global__ __launch_bounds__(256) void gather_kernel(
    const float* __restrict__ H, const int2* __restrict__ rec,
    const int* __restrict__ cursor, const int4* __restrict__ ovf,
    const int* __restrict__ ovf_cnt, float* __restrict__ out)
{
    __shared__ int2           recbuf[MAXREC];               // 16 KB
    __shared__ unsigned short order[MAXREC];                // 4 KB
    __shared__ int            rstart[ROWS_PER_BUCKET + 1];
    __shared__ int            rcur[ROWS_PER_BUCKET];
    __shared__ int            sbuf[2][ROWS_PER_BUCKET];

    int b = blockIdx.x;
    int tid = threadIdx.x;
    int rg = tid >> 4;
    int fc = tid & 15;
    const float4* H4 = reinterpret_cast<const float4*>(H);

    float4 acc[8];
    #pragma unroll
    for (int k = 0; k < 8; ++k) acc[k] = make_float4(0.f, 0.f, 0.f, 0.f);

    int p = 0;       // current cell within bucket
    int skip = 0;    // records of cell p already consumed in a previous chunk
    while (p < N_PART) {
        if (tid < ROWS_PER_BUCKET) rcur[tid] = 0;
        __syncthreads();

        // ---- fill recbuf; a cell may split across chunks via `skip` ----
        int n = 0;
        while (n < MAXREC && p < N_PART) {
            int cell = b * N_PART + p;
            int cnt = min(cursor[cell * PAD], CAP) - skip;
            int take = min(cnt, MAXREC - n);
            const int2* src = rec + cell * CAP + skip;
            for (int i = tid; i < take; i += 256) {
                int2 r = src[i];
                recbuf[n + i] = r;
                atomicAdd(&rcur[r.x >> COL_BITS], 1);
            }
            n += take;
            if (take < cnt) { skip += take; break; }  // chunk full, resume cell later
            skip = 0; ++p;                            // cell complete
        }
        __syncthreads();

        // ---- scan 128 counts -> rstart ----
        if (tid < ROWS_PER_BUCKET) sbuf[0][tid] = rcur[tid];
        __syncthreads();
        int src = 0;
        for (int off = 1; off < ROWS_PER_BUCKET; off <<= 1) {
            if (tid < ROWS_PER_BUCKET) {
                int x = sbuf[src][tid];
                if (tid >= off) x += sbuf[src][tid - off];
                sbuf[1 - src][tid] = x;
            }
            __syncthreads();
            src ^= 1;
        }
        if (tid < ROWS_PER_BUCKET) rstart[tid + 1] = sbuf[src][tid];
        if (tid == 0) rstart[0] = 0;
        __syncthreads();
        if (tid < ROWS_PER_BUCKET) rcur[tid] = rstart[tid];
        __syncthreads();

        // ---- index-sort by row ----
        for (int i = tid; i < n; i += 256) {
            int ro = recbuf[i].x >> COL_BITS;
            int pos = atomicAdd(&rcur[ro], 1);
            order[pos] = (unsigned short)i;
        }
        __syncthreads();

        // ---- register-accumulate gather ----
        #pragma unroll
        for (int k = 0; k < 8; ++k) {
            int ro = k * 16 + rg;
            int s = rstart[ro], e2 = rstart[ro + 1];
            int i = s;
            for (; i + 4 <= e2; i += 4) {
                int j0 = order[i], j1 = order[i + 1];
                int j2 = order[i + 2], j3 = order[i + 3];
                int2 r0 = recbuf[j0];
                int2 r1 = recbuf[j1];
                int2 r2 = recbuf[j2];
                int2 r3 = recbuf[j3];
                float4 h0 = H4[(r0.x & COL_MASK) * 16 + fc];
                float4 h1 = H4[(r1.x & COL_MASK) * 16 + fc];
                float4 h2 = H4[(r2.x & COL_MASK) * 16 + fc];
                float4 h3 = H4[(r3.x & COL_MASK) * 16 + fc];
                float v0 = __int_as_float(r0.y);
                float v1 = __int_as_float(r1.y);
                float v2 = __int_as_float(r2.y);
                float v3 = __int_as_float(r3.y);
                acc[k].x += v0 * h0.x; acc[k].y += v0 * h0.y;
                acc[k].z += v0 * h0.z; acc[k].w += v0 * h0.w;
                acc[k].x += v1 * h1.x; acc[k].y += v1 * h1.y;
                acc[k].z += v1 * h1.z; acc[k].w += v1 * h1.w;
                acc[k].x += v2 * h2.x; acc[k].y += v2 * h2.y;
                acc[k].z += v2 * h2.z; acc[k].w += v2 * h2.w;
                acc[k].x += v3 * h3.x; acc[k].y += v3 * h3.y;
                acc[k].z += v3 * h3.z; acc[k].w += v3 * h3.w;
            }
            for (; i < e2; ++i) {
                int j0 = order[i];
                int2 r0 = recbuf[j0];
                float4 h0 = H4[(r0.x & COL_MASK) * 16 + fc];
                float v0 = __int_as_float(r0.y);
                acc[k].x += v0 * h0.x; acc[k].y += v0 * h0.y;
                acc[k].z += v0 * h0.z; acc[k].w += v0 * h0.w;
            }
        }
        __syncthreads();
    }

    // ---- overflow records (normally zero) ----
    int novf = min(*ovf_cnt, OVF_MAX);
    int rowbase = b * ROWS_PER_BUCKET;
    for (int i = 0; i < novf; ++i) {
        int4 o = ovf[i];
        int ro = o.x - rowbase;
        if (ro >= 0 && ro < ROWS_PER_BUCKET && (ro & 15) == rg) {
            float4 h = H4[o.y * 16 + fc];
            float v = __int_as_float(o.z);
            int k = ro >> 4;
            acc[k].x += v * h.x; acc[k].y += v * h.y;
            acc[k].z += v * h.z; acc[k].w += v * h.w;
        }
    }

    // ---- coalesced writeback, exactly once ----
    #pragma unroll
    for (int k = 0; k < 8; ++k) {
        int row = rowbase + k * 16 + rg;
        if (row < N_NODES)
            reinterpret_cast<float4*>(out)[row * 16 + fc] = acc[k];
    }
}

extern "C" void kernel_launch(void* const* d_in, const int* in_sizes, int n_in,
                              void* d_out, int out_size, void* d_ws, size_t ws_size,
                              hipStream_t stream) {
    const float* H    = (const float*)d_in[0];
    const float* vals = (const float*)d_in[1];
    const int*   rows = (const int*)d_in[2];
    const int*   cols = (const int*)d_in[3];
    float* out = (float*)d_out;

    char* ws = (char*)d_ws;
    int2* rec     = (int2*)ws;                         // N_CELL*CAP*8B = 25.6 MB
    int*  cursor  = (int*)(rec + N_CELL * CAP);        // N_CELL*PAD = 400 KB
    int*  ovf_cnt = cursor + N_CELL * PAD;             // 16 ints
    int4* ovf     = (int4*)(ovf_cnt + 16);             // OVF_MAX*16B = 64 KB

    hipMemsetAsync(cursor, 0, (N_CELL * PAD + 16) * sizeof(int), stream);

    scatter_kernel<<<2048, 256, 0, stream>>>(vals, rows, cols, cursor, rec, ovf, ovf_cnt);
    gather_kernel<<<N_BUCKET, 256, 0, stream>>>(H, rec, cursor, ovf, ovf_cnt, out);
}

// Round 12
// 203.529 us; speedup vs baseline: 1.1649x; 1.1649x over previous
//
#include <hip/hip_runtime.h>

#define N_NODES 100000
#define N_EDGES 1600000
#define D_FEAT 64

#define N_PART 8
#define SLICE  (N_EDGES / N_PART)          // 200000, exact

#define RB_LOG 7
#define ROWS_PER_BUCKET 128
#define N_BUCKET ((N_NODES + ROWS_PER_BUCKET - 1) / ROWS_PER_BUCKET)  // 782
#define N_CELL (N_BUCKET * N_PART)         // 6256

#define COL_BITS 17
#define COL_MASK ((1 << COL_BITS) - 1)

#define CAP 512        // slots per (bucket,part) cell; mean 256
#define MAXREC 4096    // whole mean bucket (2048) sorts in ONE chunk
#define PAD 16
#define OVF_MAX 4096

#define TILE 2048                                   // edges per scatter block
#define EPT (TILE / 256)                            // 8 edges per thread
#define SBLK_PER_PART ((SLICE + TILE - 1) / TILE)   // 98

// ------- scatter: LDS-binned tile, one global atomic per (tile,cell) -------
__global__ __launch_bounds__(256) void scatter_kernel(
    const float* __restrict__ vals, const int* __restrict__ rows,
    const int* __restrict__ cols, int* __restrict__ cursor,
    int2* __restrict__ rec, int4* __restrict__ ovf, int* __restrict__ ovf_cnt)
{
    __shared__ int hcnt[N_BUCKET];
    __shared__ int hbase[N_BUCKET];

    int part = blockIdx.x & (N_PART - 1);
    int blk  = blockIdx.x >> 3;          // 0..97
    int base = part * SLICE;
    int t0 = blk * TILE;

    for (int i = threadIdx.x; i < N_BUCKET; i += 256) hcnt[i] = 0;
    __syncthreads();

    // load EPT edges per thread (stride-256 coalesced), rank within tile
    int r[EPT], c[EPT], rk[EPT], bb[EPT];
    float v[EPT];
    #pragma unroll
    for (int j = 0; j < EPT; ++j) {
        int e = t0 + j * 256 + threadIdx.x;
        if (e < SLICE) {
            int idx = base + e;
            r[j] = rows[idx];
            c[j] = cols[idx];
            v[j] = vals[idx];
            bb[j] = r[j] >> RB_LOG;
            rk[j] = atomicAdd(&hcnt[bb[j]], 1);
        } else {
            bb[j] = -1;
        }
    }
    __syncthreads();

    // one global atomic per nonempty cell reserves a contiguous range
    for (int i = threadIdx.x; i < N_BUCKET; i += 256) {
        int cnt = hcnt[i];
        if (cnt) hbase[i] = atomicAdd(&cursor[(i * N_PART + part) * PAD], cnt);
    }
    __syncthreads();

    // write records to reserved slots (runs of ~5 contiguous records)
    #pragma unroll
    for (int j = 0; j < EPT; ++j) {
        if (bb[j] >= 0) {
            int pos = hbase[bb[j]] + rk[j];
            if (pos < CAP) {
                int cell = bb[j] * N_PART + part;
                int packed = ((r[j] & (ROWS_PER_BUCKET - 1)) << COL_BITS) | c[j];
                rec[cell * CAP + pos] = make_int2(packed, __float_as_int(v[j]));
            } else {
                int opos = atomicAdd(ovf_cnt, 1);
                if (opos < OVF_MAX)
                    ovf[opos] = make_int4(r[j], c[j], __float_as_int(v[j]), 0);
            }
        }
    }
}

// ---- gather: per-bucket LDS index-sort + register accumulate, 512 thr -----
__global__ __launch_bounds__(512) void gather_kernel(
    const float* __restrict__ H, const int2* __restrict__ rec,
    const int* __restrict__ cursor, const int4* __restrict__ ovf,
    const int* __restrict__ ovf_cnt, float* __restrict__ out)
{
    __shared__ int2           recbuf[MAXREC];               // 32 KB
    __shared__ unsigned short order[MAXREC];                // 8 KB
    __shared__ int            rstart[ROWS_PER_BUCKET + 1];
    __shared__ int            rcur[ROWS_PER_BUCKET];
    __shared__ int            sbuf[2][ROWS_PER_BUCKET];

    int b = blockIdx.x;
    int tid = threadIdx.x;
    int rg = tid >> 4;       // row group 0..31
    int fc = tid & 15;       // feature chunk 0..15
    const float4* H4 = reinterpret_cast<const float4*>(H);

    float4 acc[4];           // rows k*32+rg, k=0..3
    #pragma unroll
    for (int k = 0; k < 4; ++k) acc[k] = make_float4(0.f, 0.f, 0.f, 0.f);

    int p = 0;       // current cell within bucket
    int skip = 0;    // records of cell p already consumed
    while (p < N_PART) {
        if (tid < ROWS_PER_BUCKET) rcur[tid] = 0;
        __syncthreads();

        // ---- fill recbuf; a cell may split across chunks via `skip` ----
        int n = 0;
        while (n < MAXREC && p < N_PART) {
            int cell = b * N_PART + p;
            int cnt = min(cursor[cell * PAD], CAP) - skip;
            int take = min(cnt, MAXREC - n);
            const int2* src = rec + cell * CAP + skip;
            for (int i = tid; i < take; i += 512) {
                int2 r = src[i];
                recbuf[n + i] = r;
                atomicAdd(&rcur[r.x >> COL_BITS], 1);
            }
            n += take;
            if (take < cnt) { skip += take; break; }
            skip = 0; ++p;
        }
        __syncthreads();

        // ---- scan 128 counts -> rstart ----
        if (tid < ROWS_PER_BUCKET) sbuf[0][tid] = rcur[tid];
        __syncthreads();
        int src = 0;
        for (int off = 1; off < ROWS_PER_BUCKET; off <<= 1) {
            if (tid < ROWS_PER_BUCKET) {
                int x = sbuf[src][tid];
                if (tid >= off) x += sbuf[src][tid - off];
                sbuf[1 - src][tid] = x;
            }
            __syncthreads();
            src ^= 1;
        }
        if (tid < ROWS_PER_BUCKET) rstart[tid + 1] = sbuf[src][tid];
        if (tid == 0) rstart[0] = 0;
        __syncthreads();
        if (tid < ROWS_PER_BUCKET) rcur[tid] = rstart[tid];
        __syncthreads();

        // ---- index-sort by row ----
        for (int i = tid; i < n; i += 512) {
            int ro = recbuf[i].x >> COL_BITS;
            int pos = atomicAdd(&rcur[ro], 1);
            order[pos] = (unsigned short)i;
        }
        __syncthreads();

        // ---- register-accumulate gather ----
        #pragma unroll
        for (int k = 0; k < 4; ++k) {
            int ro = k * 32 + rg;
            int s = rstart[ro], e2 = rstart[ro + 1];
            int i = s;
            for (; i + 4 <= e2; i += 4) {
                int j0 = order[i], j1 = order[i + 1];
                int j2 = order[i + 2], j3 = order[i + 3];
                int2 r0 = recbuf[j0];
                int2 r1 = recbuf[j1];
                int2 r2 = recbuf[j2];
                int2 r3 = recbuf[j3];
                float4 h0 = H4[(r0.x & COL_MASK) * 16 + fc];
                float4 h1 = H4[(r1.x & COL_MASK) * 16 + fc];
                float4 h2 = H4[(r2.x & COL_MASK) * 16 + fc];
                float4 h3 = H4[(r3.x & COL_MASK) * 16 + fc];
                float v0 = __int_as_float(r0.y);
                float v1 = __int_as_float(r1.y);
                float v2 = __int_as_float(r2.y);
                float v3 = __int_as_float(r3.y);
                acc[k].x += v0 * h0.x; acc[k].y += v0 * h0.y;
                acc[k].z += v0 * h0.z; acc[k].w += v0 * h0.w;
                acc[k].x += v1 * h1.x; acc[k].y += v1 * h1.y;
                acc[k].z += v1 * h1.z; acc[k].w += v1 * h1.w;
                acc[k].x += v2 * h2.x; acc[k].y += v2 * h2.y;
                acc[k].z += v2 * h2.z; acc[k].w += v2 * h2.w;
                acc[k].x += v3 * h3.x; acc[k].y += v3 * h3.y;
                acc[k].z += v3 * h3.z; acc[k].w += v3 * h3.w;
            }
            for (; i < e2; ++i) {
                int j0 = order[i];
                int2 r0 = recbuf[j0];
                float4 h0 = H4[(r0.x & COL_MASK) * 16 + fc];
                float v0 = __int_as_float(r0.y);
                acc[k].x += v0 * h0.x; acc[k].y += v0 * h0.y;
                acc[k].z += v0 * h0.z; acc[k].w += v0 * h0.w;
            }
        }
        __syncthreads();
    }

    // ---- overflow records (normally zero) ----
    int novf = min(*ovf_cnt, OVF_MAX);
    int rowbase = b * ROWS_PER_BUCKET;
    for (int i = 0; i < novf; ++i) {
        int4 o = ovf[i];
        int ro = o.x - rowbase;
        if (ro >= 0 && ro < ROWS_PER_BUCKET && (ro & 31) == rg) {
            float4 h = H4[o.y * 16 + fc];
            float v = __int_as_float(o.z);
            int k = ro >> 5;
            acc[k].x += v * h.x; acc[k].y += v * h.y;
            acc[k].z += v * h.z; acc[k].w += v * h.w;
        }
    }

    // ---- coalesced writeback, exactly once ----
    #pragma unroll
    for (int k = 0; k < 4; ++k) {
        int row = rowbase + k * 32 + rg;
        if (row < N_NODES)
            reinterpret_cast<float4*>(out)[row * 16 + fc] = acc[k];
    }
}

extern "C" void kernel_launch(void* const* d_in, const int* in_sizes, int n_in,
                              void* d_out, int out_size, void* d_ws, size_t ws_size,
                              hipStream_t stream) {
    const float* H    = (const float*)d_in[0];
    const float* vals = (const float*)d_in[1];
    const int*   rows = (const int*)d_in[2];
    const int*   cols = (const int*)d_in[3];
    float* out = (float*)d_out;

    char* ws = (char*)d_ws;
    int2* rec     = (int2*)ws;                         // N_CELL*CAP*8B = 25.6 MB
    int*  cursor  = (int*)(rec + N_CELL * CAP);        // N_CELL*PAD
    int*  ovf_cnt = cursor + N_CELL * PAD;             // 16 ints
    int4* ovf     = (int4*)(ovf_cnt + 16);             // OVF_MAX*16B

    hipMemsetAsync(cursor, 0, (N_CELL * PAD + 16) * sizeof(int), stream);

    scatter_kernel<<<SBLK_PER_PART * N_PART, 256, 0, stream>>>(
        vals, rows, cols, cursor, rec, ovf, ovf_cnt);
    gather_kernel<<<N_BUCKET, 512, 0, stream>>>(H, rec, cursor, ovf, ovf_cnt, out);
}